// Round 1
// baseline (524.655 us; speedup 1.0000x reference)
//
#include <hip/hip_runtime.h>

typedef _Float16 f16;
typedef f16 f16x4 __attribute__((ext_vector_type(4)));
typedef f16 f16x8 __attribute__((ext_vector_type(8)));
typedef float f32x4 __attribute__((ext_vector_type(4)));

// ---------------- cast fp32 -> fp16 (vectorized) ----------------
__global__ void k_cast(const float* __restrict__ src, f16* __restrict__ dst, int n4) {
    int i = blockIdx.x * 256 + threadIdx.x;
    if (i < n4) {
        f32x4 v = *(const f32x4*)(src + (size_t)i * 4);
        f16x4 h = { (f16)v[0], (f16)v[1], (f16)v[2], (f16)v[3] };
        *(f16x4*)(dst + (size_t)i * 4) = h;
    }
}

// ---------------- transpose + cast: src[R][C] f32 -> dst[C][R] f16 ----------------
__global__ __launch_bounds__(256) void k_transpose_cast(const float* __restrict__ src,
                                                        f16* __restrict__ dst, int R, int C) {
    __shared__ float tile[32 * 33];
    int tx = threadIdx.x & 31, ty = threadIdx.x >> 5;
    int c0 = blockIdx.x * 32, r0 = blockIdx.y * 32;
#pragma unroll
    for (int i = 0; i < 4; ++i) {
        int r = ty + i * 8;
        tile[r * 33 + tx] = src[(size_t)(r0 + r) * C + c0 + tx];
    }
    __syncthreads();
#pragma unroll
    for (int i = 0; i < 4; ++i) {
        int rr = ty + i * 8;
        dst[(size_t)(c0 + rr) * R + r0 + tx] = (f16)tile[tx * 33 + rr];
    }
}

// ---------------- fp16 MFMA GEMM: C[M][N] = A[M][K] @ Bt[N][K]^T + bias ----------------
// m97-style: 128x128 tile, BK=64, 4 waves, global_load_lds width 16, linear LDS.
__global__ __launch_bounds__(256) void k_gemm(const f16* __restrict__ A, const f16* __restrict__ Bt,
                                              const float* __restrict__ bias, float* __restrict__ C,
                                              f16* __restrict__ Ch, int M, int N, int K) {
    __shared__ f16 As[128 * 64];
    __shared__ f16 Bs[128 * 64];
    const int tid = threadIdx.x;
    const int lane = tid & 63, wave = tid >> 6;
    const int wr = wave >> 1, wc = wave & 1;
    const int m0 = blockIdx.y * 128, n0 = blockIdx.x * 128;
    const int lr = lane & 15, lq = lane >> 4;
    f32x4 acc[4][4] = {};
    for (int k0 = 0; k0 < K; k0 += 64) {
        __syncthreads();
#pragma unroll
        for (int r = 0; r < 4; ++r) {
            int o = r * 4096 + tid * 16;
            int row = o >> 7;
            int kb = (o & 127) >> 1;
            __builtin_amdgcn_global_load_lds(
                (const __attribute__((address_space(1))) void*)(A + (size_t)(m0 + row) * K + k0 + kb),
                (__attribute__((address_space(3))) void*)((char*)As + o), 16, 0, 0);
        }
#pragma unroll
        for (int r = 0; r < 4; ++r) {
            int o = r * 4096 + tid * 16;
            int row = o >> 7;
            int kb = (o & 127) >> 1;
            __builtin_amdgcn_global_load_lds(
                (const __attribute__((address_space(1))) void*)(Bt + (size_t)(n0 + row) * K + k0 + kb),
                (__attribute__((address_space(3))) void*)((char*)Bs + o), 16, 0, 0);
        }
        __syncthreads();
#pragma unroll
        for (int ks = 0; ks < 2; ++ks) {
            f16x8 af[4], bf[4];
#pragma unroll
            for (int m = 0; m < 4; ++m)
                af[m] = *(const f16x8*)&As[(wr * 64 + m * 16 + lr) * 64 + ks * 32 + lq * 8];
#pragma unroll
            for (int n = 0; n < 4; ++n)
                bf[n] = *(const f16x8*)&Bs[(wc * 64 + n * 16 + lr) * 64 + ks * 32 + lq * 8];
#pragma unroll
            for (int m = 0; m < 4; ++m)
#pragma unroll
                for (int n = 0; n < 4; ++n)
                    acc[m][n] = __builtin_amdgcn_mfma_f32_16x16x32_f16(af[m], bf[n], acc[m][n], 0, 0, 0);
        }
    }
#pragma unroll
    for (int m = 0; m < 4; ++m) {
#pragma unroll
        for (int n = 0; n < 4; ++n) {
            int col = n0 + wc * 64 + n * 16 + lr;
            float bcol = bias[col];
#pragma unroll
            for (int j = 0; j < 4; ++j) {
                int row = m0 + wr * 64 + m * 16 + lq * 4 + j;
                float v = acc[m][n][j] + bcol;
                C[(size_t)row * N + col] = v;
                Ch[(size_t)row * N + col] = (f16)v;
            }
        }
    }
}

// ---------------- ||Sr[b,:,d]|| over L=32 ----------------
__global__ void k_srnorm(const float* __restrict__ Sr, float* __restrict__ SrNorm) {
    int idx = blockIdx.x * 256 + threadIdx.x; // 16384
    int b = idx >> 10, d = idx & 1023;
    float s = 0.f;
#pragma unroll
    for (int l = 0; l < 32; ++l) {
        float v = Sr[((size_t)(b * 32 + l)) * 1024 + d];
        s += v * v;
    }
    SrNorm[idx] = sqrtf(s);
}

// ---------------- per-(b,seg): S = Srh @ Vrh^T (MFMA), softmax stats, W = P @ Vr ----------------
__global__ __launch_bounds__(256) void k_seg(const float* __restrict__ Vr, const f16* __restrict__ Vrh,
                                             const f16* __restrict__ Srh, float* __restrict__ W,
                                             float* __restrict__ Mg, float* __restrict__ Eg) {
    const int b = blockIdx.x >> 4, k = blockIdx.x & 15;
    __shared__ float Sm[32 * 26];
    __shared__ float P[32 * 25];
    __shared__ float VrB[25 * 260];
    const int tid = threadIdx.x;
    const int lane = tid & 63, wave = tid >> 6;
    // phase A: S[32][25] = Srh[b] (32x1024) x Vrh[b,seg]^T, frags direct from global
    {
        const int mf = wave >> 1, nf = wave & 1;
        const int lr = lane & 15, lq = lane >> 4;
        f32x4 acc = {};
        const f16* arow = Srh + ((size_t)(b * 32 + mf * 16 + lr)) * 1024 + lq * 8;
        const f16* brow = Vrh + ((size_t)(b * 400 + k * 25 + nf * 16 + lr)) * 1024 + lq * 8;
        for (int k0 = 0; k0 < 1024; k0 += 32) {
            f16x8 a = *(const f16x8*)(arow + k0);
            f16x8 bb = *(const f16x8*)(brow + k0);
            acc = __builtin_amdgcn_mfma_f32_16x16x32_f16(a, bb, acc, 0, 0, 0);
        }
        int t = nf * 16 + lr;
        if (t < 25) {
#pragma unroll
            for (int j = 0; j < 4; ++j) {
                int l = mf * 16 + lq * 4 + j;
                Sm[l * 26 + t] = acc[j];
            }
        }
    }
    __syncthreads();
    if (tid < 32) {
        int l = tid;
        float m = Sm[l * 26];
        for (int t = 1; t < 25; ++t) m = fmaxf(m, Sm[l * 26 + t]);
        float e = 0.f;
        for (int t = 0; t < 25; ++t) {
            float p = __expf(Sm[l * 26 + t] - m);
            P[l * 25 + t] = p;
            e += p;
        }
        Mg[(b * 16 + k) * 32 + l] = m;
        Eg[(b * 16 + k) * 32 + l] = e;
    }
    __syncthreads();
    // phase B: W[b][l][k][d] = sum_t P[l][t] * Vr[b, seg_t][d]   (fp32)
    const int dl = tid & 63, q = tid >> 6;
    for (int c = 0; c < 4; ++c) {
#pragma unroll
        for (int ii = 0; ii < 25; ++ii) {
            int idx = tid + ii * 256;
            int row = idx >> 8, dd = idx & 255;
            VrB[row * 260 + dd] = Vr[((size_t)(b * 400 + k * 25 + row)) * 1024 + c * 256 + dd];
        }
        __syncthreads();
        f32x4 accw[8] = {};
        for (int t = 0; t < 25; ++t) {
            f32x4 v = *(const f32x4*)&VrB[t * 260 + dl * 4];
#pragma unroll
            for (int li = 0; li < 8; ++li) {
                float p = P[(q + li * 4) * 25 + t];
                accw[li][0] += p * v[0];
                accw[li][1] += p * v[1];
                accw[li][2] += p * v[2];
                accw[li][3] += p * v[3];
            }
        }
#pragma unroll
        for (int li = 0; li < 8; ++li) {
            int l = q + li * 4;
            *(f32x4*)&W[(((size_t)(b * 32 + l)) * 16 + k) * 1024 + c * 256 + dl * 4] = accw[li];
        }
        __syncthreads();
    }
}

// ---------------- per-b: EM = exp(M-G), rden[p][l] = 1/sum_{k in win} EM*E ----------------
__global__ __launch_bounds__(512) void k_alpha(const float* __restrict__ Mg, const float* __restrict__ Eg,
                                               float* __restrict__ EMg, float* __restrict__ rdeng) {
    const int b = blockIdx.x;
    __shared__ float EE[32 * 16];
    __shared__ int pS[136], pE[136];
    const int tid = threadIdx.x;
    if (tid < 136) {
        int s = 0, rem = tid;
        while (rem >= 16 - s) { rem -= 16 - s; ++s; }
        pS[tid] = s;
        pE[tid] = s + rem;
    }
    if (tid < 32) {
        int l = tid;
        float G = -1e30f;
#pragma unroll
        for (int k = 0; k < 16; ++k) G = fmaxf(G, Mg[(b * 16 + k) * 32 + l]);
#pragma unroll
        for (int k = 0; k < 16; ++k) {
            float em = __expf(Mg[(b * 16 + k) * 32 + l] - G);
            EMg[((size_t)(b * 32 + l)) * 16 + k] = em;
            EE[l * 16 + k] = em * Eg[(b * 16 + k) * 32 + l];
        }
    }
    __syncthreads();
    for (int it = tid; it < 136 * 32; it += 512) {
        int p = it >> 5, l = it & 31;
        float den = 0.f;
        int s = pS[p], e = pE[p];
        for (int k = s; k <= e; ++k) den += EE[l * 16 + k];
        rdeng[((size_t)(b * 136) + p) * 32 + l] = 1.0f / (den + 1e-30f);
    }
}

// ---------------- combine: out,num,ssq,score,positive,negative ----------------
__global__ __launch_bounds__(512) void k_combine(const float* __restrict__ W, const float* __restrict__ EMg,
                                                 const float* __restrict__ rdeng, const float* __restrict__ Sr,
                                                 const float* __restrict__ SrNorm, const int* __restrict__ ytrue,
                                                 float* __restrict__ out, unsigned int* __restrict__ negk) {
    extern __shared__ float sm[];
    float* rden_s = sm;           // 4352
    float* EM_s = sm + 4352;      // 512
    float* srn_s = sm + 4864;     // 64
    float* wmax_s = sm + 4928;    // 8
    float* num_s = sm + 4936;     // 8704
    float* ssq_s = num_s + 8704;  // 8704
    const int b = blockIdx.x >> 4, dc = blockIdx.x & 15;
    const int tid = threadIdx.x, lane = tid & 63, wave = tid >> 6;
    for (int i = tid; i < 4352; i += 512) rden_s[i] = rdeng[(size_t)b * 4352 + i];
    EM_s[tid & 511] = EMg[(size_t)b * 512 + (tid & 511)];
    if (tid < 64) srn_s[tid] = SrNorm[b * 1024 + dc * 64 + tid];
    for (int i = tid; i < 2 * 8704; i += 512) num_s[i] = 0.f;
    const int sy = ytrue[b * 2], ey = ytrue[b * 2 + 1];
    const int pm = sy * 16 - (sy * (sy - 1)) / 2 + (ey - sy);
    __syncthreads();
    const int d = dc * 64 + lane;
    float v[4][16];
    float sr4[4];
#pragma unroll
    for (int li = 0; li < 4; ++li) {
        const int l = wave * 4 + li;
#pragma unroll
        for (int kk = 0; kk < 16; ++kk)
            v[li][kk] = W[(((size_t)(b * 32 + l)) * 16 + kk) * 1024 + d] * EM_s[l * 16 + kk];
        sr4[li] = Sr[((size_t)(b * 32 + l)) * 1024 + d];
    }
#pragma unroll
    for (int s = 0; s < 16; ++s) {
        float s0 = 0.f, s1 = 0.f, s2 = 0.f, s3 = 0.f;
#pragma unroll
        for (int e = s; e < 16; ++e) {
            const int p = s * 16 - (s * (s - 1)) / 2 + (e - s);
            s0 += v[0][e];
            s1 += v[1][e];
            s2 += v[2][e];
            s3 += v[3][e];
            f32x4 rd = *(const f32x4*)&rden_s[p * 32 + wave * 4];
            float o0 = s0 * rd[0], o1 = s1 * rd[1], o2 = s2 * rd[2], o3 = s3 * rd[3];
            float np = o0 * sr4[0] + o1 * sr4[1] + o2 * sr4[2] + o3 * sr4[3];
            float sp = o0 * o0 + o1 * o1 + o2 * o2 + o3 * o3;
            atomicAdd(&num_s[p * 64 + lane], np);
            atomicAdd(&ssq_s[p * 64 + lane], sp);
        }
    }
    __syncthreads();
    float lmax = -1e30f;
#pragma unroll
    for (int i = 0; i < 17; ++i) {
        int idx = tid + i * 512;
        int p = idx >> 6, dd = idx & 63;
        float score = num_s[idx] / (sqrtf(ssq_s[idx]) * srn_s[dd] + 1e-15f);
        if (p == pm) out[b * 1024 + dc * 64 + dd] = score;
        else lmax = fmaxf(lmax, score);
    }
#pragma unroll
    for (int off = 32; off >= 1; off >>= 1) lmax = fmaxf(lmax, __shfl_xor(lmax, off));
    if (lane == 0) wmax_s[wave] = lmax;
    __syncthreads();
    if (tid == 0) {
        float m = wmax_s[0];
#pragma unroll
        for (int w = 1; w < 8; ++w) m = fmaxf(m, wmax_s[w]);
        unsigned u = __float_as_uint(m);
        unsigned key = (u & 0x80000000u) ? ~u : (u | 0x80000000u);
        atomicMax(&negk[b], key);
    }
}

__global__ void k_init(unsigned* __restrict__ negk) {
    if (threadIdx.x < 16) negk[threadIdx.x] = 0u;
}

__global__ void k_negout(const unsigned* __restrict__ negk, float* __restrict__ out) {
    int i = threadIdx.x;
    if (i < 16) {
        unsigned key = negk[i];
        unsigned u = (key & 0x80000000u) ? (key ^ 0x80000000u) : ~key;
        out[16384 + i] = __uint_as_float(u);
    }
}

extern "C" void kernel_launch(void* const* d_in, const int* in_sizes, int n_in,
                              void* d_out, int out_size, void* d_ws, size_t ws_size,
                              hipStream_t stream) {
    const float* videos = (const float*)d_in[0];
    const float* sentences = (const float*)d_in[1];
    const float* Wv = (const float*)d_in[2];
    const float* bv = (const float*)d_in[3];
    const float* Ws = (const float*)d_in[4];
    const float* bs = (const float*)d_in[5];
    const int* ytrue = (const int*)d_in[6];
    float* out = (float*)d_out;

    char* ws = (char*)d_ws;
    size_t off = 0;
    auto alloc = [&](size_t bytes) {
        char* p = ws + off;
        off = (off + bytes + 255) & ~(size_t)255;
        return p;
    };
    f16* vh = (f16*)alloc(52428800);      // videos fp16 [6400][4096]
    f16* wvt = (f16*)alloc(8388608);      // Wv^T fp16 [1024][4096]
    f16* sh = (f16*)alloc(786432);        // sentences fp16 [512][768]
    f16* wst = (f16*)alloc(1572864);      // Ws^T fp16 [1024][768]
    float* Vr = (float*)alloc(26214400);  // [6400][1024] f32
    f16* Vrh = (f16*)alloc(13107200);     // [6400][1024] f16
    float* Sr = (float*)alloc(2097152);   // [512][1024] f32
    f16* Srh = (f16*)alloc(1048576);      // [512][1024] f16
    float* W = (float*)alloc(33554432);   // [16][32][16][1024] f32
    float* Mg = (float*)alloc(32768);     // [16][16][32]
    float* Eg = (float*)alloc(32768);
    float* EMg = (float*)alloc(32768);    // [16][32][16]
    float* rdeng = (float*)alloc(278528); // [16][136][32]
    float* SrNorm = (float*)alloc(65536); // [16][1024]
    unsigned* negk = (unsigned*)alloc(64);
    if (off > ws_size) return; // workspace too small: fail loudly via wrong output

    hipLaunchKernelGGL(k_init, dim3(1), dim3(64), 0, stream, negk);
    hipLaunchKernelGGL(k_cast, dim3(6553600 / 256), dim3(256), 0, stream, videos, vh, 6553600);
    hipLaunchKernelGGL(k_cast, dim3(98304 / 256), dim3(256), 0, stream, sentences, sh, 98304);
    hipLaunchKernelGGL(k_transpose_cast, dim3(32, 128), dim3(256), 0, stream, Wv, wvt, 4096, 1024);
    hipLaunchKernelGGL(k_transpose_cast, dim3(32, 24), dim3(256), 0, stream, Ws, wst, 768, 1024);
    hipLaunchKernelGGL(k_gemm, dim3(8, 50), dim3(256), 0, stream, vh, wvt, bv, Vr, Vrh, 6400, 1024, 4096);
    hipLaunchKernelGGL(k_gemm, dim3(8, 4), dim3(256), 0, stream, sh, wst, bs, Sr, Srh, 512, 1024, 768);
    hipLaunchKernelGGL(k_srnorm, dim3(64), dim3(256), 0, stream, Sr, SrNorm);
    hipLaunchKernelGGL(k_seg, dim3(256), dim3(256), 0, stream, Vr, Vrh, Srh, W, Mg, Eg);
    hipLaunchKernelGGL(k_alpha, dim3(16), dim3(512), 0, stream, Mg, Eg, EMg, rdeng);
    hipLaunchKernelGGL(k_combine, dim3(256), dim3(512), 89376, stream, W, EMg, rdeng, Sr, SrNorm, ytrue, out, negk);
    hipLaunchKernelGGL(k_negout, dim3(1), dim3(64), 0, stream, negk, out);
}

// Round 3
// 360.698 us; speedup vs baseline: 1.4546x; 1.4546x over previous
//
#include <hip/hip_runtime.h>

typedef _Float16 f16;
typedef f16 f16x4 __attribute__((ext_vector_type(4)));
typedef f16 f16x8 __attribute__((ext_vector_type(8)));
typedef float f32x4 __attribute__((ext_vector_type(4)));

// ---------------- cast fp32 -> fp16 (vectorized) ----------------
__global__ void k_cast(const float* __restrict__ src, f16* __restrict__ dst, int n4) {
    int i = blockIdx.x * 256 + threadIdx.x;
    if (i < n4) {
        f32x4 v = *(const f32x4*)(src + (size_t)i * 4);
        f16x4 h = { (f16)v[0], (f16)v[1], (f16)v[2], (f16)v[3] };
        *(f16x4*)(dst + (size_t)i * 4) = h;
    }
}

// ---------------- transpose + cast: src[R][C] f32 -> dst[C][R] f16 ----------------
__global__ __launch_bounds__(256) void k_transpose_cast(const float* __restrict__ src,
                                                        f16* __restrict__ dst, int R, int C) {
    __shared__ float tile[32 * 33];
    int tx = threadIdx.x & 31, ty = threadIdx.x >> 5;
    int c0 = blockIdx.x * 32, r0 = blockIdx.y * 32;
#pragma unroll
    for (int i = 0; i < 4; ++i) {
        int r = ty + i * 8;
        tile[r * 33 + tx] = src[(size_t)(r0 + r) * C + c0 + tx];
    }
    __syncthreads();
#pragma unroll
    for (int i = 0; i < 4; ++i) {
        int rr = ty + i * 8;
        dst[(size_t)(c0 + rr) * R + r0 + tx] = (f16)tile[tx * 33 + rr];
    }
}

// ---------------- fp16 MFMA GEMM: C[M][N] = A[M][K] @ Bt[N][K]^T + bias ----------------
__global__ __launch_bounds__(256) void k_gemm(const f16* __restrict__ A, const f16* __restrict__ Bt,
                                              const float* __restrict__ bias, float* __restrict__ C,
                                              f16* __restrict__ Ch, int M, int N, int K) {
    __shared__ f16 As[128 * 64];
    __shared__ f16 Bs[128 * 64];
    const int tid = threadIdx.x;
    const int lane = tid & 63, wave = tid >> 6;
    const int wr = wave >> 1, wc = wave & 1;
    const int m0 = blockIdx.y * 128, n0 = blockIdx.x * 128;
    const int lr = lane & 15, lq = lane >> 4;
    f32x4 acc[4][4] = {};
    for (int k0 = 0; k0 < K; k0 += 64) {
        __syncthreads();
#pragma unroll
        for (int r = 0; r < 4; ++r) {
            int o = r * 4096 + tid * 16;
            int row = o >> 7;
            int kb = (o & 127) >> 1;
            __builtin_amdgcn_global_load_lds(
                (const __attribute__((address_space(1))) void*)(A + (size_t)(m0 + row) * K + k0 + kb),
                (__attribute__((address_space(3))) void*)((char*)As + o), 16, 0, 0);
        }
#pragma unroll
        for (int r = 0; r < 4; ++r) {
            int o = r * 4096 + tid * 16;
            int row = o >> 7;
            int kb = (o & 127) >> 1;
            __builtin_amdgcn_global_load_lds(
                (const __attribute__((address_space(1))) void*)(Bt + (size_t)(n0 + row) * K + k0 + kb),
                (__attribute__((address_space(3))) void*)((char*)Bs + o), 16, 0, 0);
        }
        __syncthreads();
#pragma unroll
        for (int ks = 0; ks < 2; ++ks) {
            f16x8 af[4], bf[4];
#pragma unroll
            for (int m = 0; m < 4; ++m)
                af[m] = *(const f16x8*)&As[(wr * 64 + m * 16 + lr) * 64 + ks * 32 + lq * 8];
#pragma unroll
            for (int n = 0; n < 4; ++n)
                bf[n] = *(const f16x8*)&Bs[(wc * 64 + n * 16 + lr) * 64 + ks * 32 + lq * 8];
#pragma unroll
            for (int m = 0; m < 4; ++m)
#pragma unroll
                for (int n = 0; n < 4; ++n)
                    acc[m][n] = __builtin_amdgcn_mfma_f32_16x16x32_f16(af[m], bf[n], acc[m][n], 0, 0, 0);
        }
    }
#pragma unroll
    for (int m = 0; m < 4; ++m) {
#pragma unroll
        for (int n = 0; n < 4; ++n) {
            int col = n0 + wc * 64 + n * 16 + lr;
            float bcol = bias[col];
#pragma unroll
            for (int j = 0; j < 4; ++j) {
                int row = m0 + wr * 64 + m * 16 + lq * 4 + j;
                float v = acc[m][n][j] + bcol;
                C[(size_t)row * N + col] = v;
                Ch[(size_t)row * N + col] = (f16)v;
            }
        }
    }
}

// ---------------- ||Sr[b,:,d]|| over L=32 ----------------
__global__ void k_srnorm(const float* __restrict__ Sr, float* __restrict__ SrNorm) {
    int idx = blockIdx.x * 256 + threadIdx.x; // 16384
    int b = idx >> 10, d = idx & 1023;
    float s = 0.f;
#pragma unroll
    for (int l = 0; l < 32; ++l) {
        float v = Sr[((size_t)(b * 32 + l)) * 1024 + d];
        s += v * v;
    }
    SrNorm[idx] = sqrtf(s);
}

// ---------------- per-(b,seg): S = Srh @ Vrh^T (MFMA), softmax stats, W = P @ Vr ----------------
__global__ __launch_bounds__(256) void k_seg(const float* __restrict__ Vr, const f16* __restrict__ Vrh,
                                             const f16* __restrict__ Srh, float* __restrict__ W,
                                             float* __restrict__ Mg, float* __restrict__ Eg) {
    const int b = blockIdx.x >> 4, k = blockIdx.x & 15;
    __shared__ float Sm[32 * 26];
    __shared__ float P[32 * 25];
    __shared__ float VrB[25 * 260];
    const int tid = threadIdx.x;
    const int lane = tid & 63, wave = tid >> 6;
    {
        const int mf = wave >> 1, nf = wave & 1;
        const int lr = lane & 15, lq = lane >> 4;
        f32x4 acc = {};
        const f16* arow = Srh + ((size_t)(b * 32 + mf * 16 + lr)) * 1024 + lq * 8;
        const f16* brow = Vrh + ((size_t)(b * 400 + k * 25 + nf * 16 + lr)) * 1024 + lq * 8;
        for (int k0 = 0; k0 < 1024; k0 += 32) {
            f16x8 a = *(const f16x8*)(arow + k0);
            f16x8 bb = *(const f16x8*)(brow + k0);
            acc = __builtin_amdgcn_mfma_f32_16x16x32_f16(a, bb, acc, 0, 0, 0);
        }
        int t = nf * 16 + lr;
        if (t < 25) {
#pragma unroll
            for (int j = 0; j < 4; ++j) {
                int l = mf * 16 + lq * 4 + j;
                Sm[l * 26 + t] = acc[j];
            }
        }
    }
    __syncthreads();
    if (tid < 32) {
        int l = tid;
        float m = Sm[l * 26];
        for (int t = 1; t < 25; ++t) m = fmaxf(m, Sm[l * 26 + t]);
        float e = 0.f;
        for (int t = 0; t < 25; ++t) {
            float p = __expf(Sm[l * 26 + t] - m);
            P[l * 25 + t] = p;
            e += p;
        }
        Mg[(b * 16 + k) * 32 + l] = m;
        Eg[(b * 16 + k) * 32 + l] = e;
    }
    __syncthreads();
    const int dl = tid & 63, q = tid >> 6;
    for (int c = 0; c < 4; ++c) {
#pragma unroll
        for (int ii = 0; ii < 25; ++ii) {
            int idx = tid + ii * 256;
            int row = idx >> 8, dd = idx & 255;
            VrB[row * 260 + dd] = Vr[((size_t)(b * 400 + k * 25 + row)) * 1024 + c * 256 + dd];
        }
        __syncthreads();
        f32x4 accw[8] = {};
        for (int t = 0; t < 25; ++t) {
            f32x4 v = *(const f32x4*)&VrB[t * 260 + dl * 4];
#pragma unroll
            for (int li = 0; li < 8; ++li) {
                float p = P[(q + li * 4) * 25 + t];
                accw[li][0] += p * v[0];
                accw[li][1] += p * v[1];
                accw[li][2] += p * v[2];
                accw[li][3] += p * v[3];
            }
        }
#pragma unroll
        for (int li = 0; li < 8; ++li) {
            int l = q + li * 4;
            *(f32x4*)&W[(((size_t)(b * 32 + l)) * 16 + k) * 1024 + c * 256 + dl * 4] = accw[li];
        }
        __syncthreads();
    }
}

// ---------------- per-b: EM = exp(M-G), rden[p][l] = 1/sum_{k in win} EM*E ----------------
__global__ __launch_bounds__(512) void k_alpha(const float* __restrict__ Mg, const float* __restrict__ Eg,
                                               float* __restrict__ EMg, float* __restrict__ rdeng) {
    const int b = blockIdx.x;
    __shared__ float EE[32 * 16];
    __shared__ int pS[136], pE[136];
    const int tid = threadIdx.x;
    if (tid < 136) {
        int s = 0, rem = tid;
        while (rem >= 16 - s) { rem -= 16 - s; ++s; }
        pS[tid] = s;
        pE[tid] = s + rem;
    }
    if (tid < 32) {
        int l = tid;
        float G = -1e30f;
#pragma unroll
        for (int k = 0; k < 16; ++k) G = fmaxf(G, Mg[(b * 16 + k) * 32 + l]);
#pragma unroll
        for (int k = 0; k < 16; ++k) {
            float em = __expf(Mg[(b * 16 + k) * 32 + l] - G);
            EMg[((size_t)(b * 32 + l)) * 16 + k] = em;
            EE[l * 16 + k] = em * Eg[(b * 16 + k) * 32 + l];
        }
    }
    __syncthreads();
    for (int it = tid; it < 136 * 32; it += 512) {
        int p = it >> 5, l = it & 31;
        float den = 0.f;
        int s = pS[p], e = pE[p];
        for (int k = s; k <= e; ++k) den += EE[l * 16 + k];
        rdeng[((size_t)(b * 136) + p) * 32 + l] = 1.0f / (den + 1e-30f);
    }
}

// ---------------- combine (atomic-free): each wave owns s in {w, 15-w}, lane owns d ----------------
// v_s[l][e][dl] = W[b][l][e][d]*EM[l][e] in 128KB dynamic LDS; per-l prefix sums over e
// held in registers (compile-time indexed); score computed fully per-thread.
__global__ __launch_bounds__(512) void k_combine(const float* __restrict__ W, const float* __restrict__ EMg,
                                                 const float* __restrict__ rdeng, const float* __restrict__ Sr,
                                                 const float* __restrict__ SrNorm, const int* __restrict__ ytrue,
                                                 float* __restrict__ out, unsigned int* __restrict__ negk) {
    extern __shared__ float v_s[]; // [32][16][64] = 32768 floats
    __shared__ float wmax_s[8];
    const int b = blockIdx.x >> 4, dc = blockIdx.x & 15;
    const int tid = threadIdx.x, lane = tid & 63, wave = tid >> 6;
    const int d = dc * 64 + lane;

    // stage v = W * EM (EM factor is wave-uniform per (l,k) -> scalar load)
#pragma unroll 4
    for (int i = 0; i < 64; ++i) {
        int idx = tid + i * 512;
        int l = idx >> 10, k = (idx >> 6) & 15;
        float em = EMg[(b * 32 + l) * 16 + k];
        v_s[idx] = W[(((size_t)(b * 32 + l)) * 16 + k) * 1024 + dc * 64 + (idx & 63)] * em;
    }
    float sr[32];
#pragma unroll
    for (int l = 0; l < 32; ++l) sr[l] = Sr[((size_t)(b * 32 + l)) * 1024 + d];
    const float srn = SrNorm[b * 1024 + d];
    const int sy = ytrue[b * 2], ey = ytrue[b * 2 + 1];
    const int pm = sy * 16 - (sy * (sy - 1)) / 2 + (ey - sy);
    __syncthreads();

    const int sA = wave, sB = 15 - wave;
    const int pA0 = sA * 16 - (sA * (sA - 1)) / 2 - sA; // pA = pA0 + e
    const int pB0 = sB * 16 - (sB * (sB - 1)) / 2 - sB;
    float runA[32], runB[32];
#pragma unroll
    for (int l = 0; l < 32; ++l) { runA[l] = 0.f; runB[l] = 0.f; }
    float lmax = -1e30f;

    for (int e = sA; e < 16; ++e) {
        const bool doB = (e >= sB);
        const int pA = pA0 + e, pB = pB0 + e;
        f32x4 rdA[8], rdB[8];
        const float* rA = rdeng + ((size_t)b * 136 + pA) * 32;
        const float* rB = rdeng + ((size_t)b * 136 + pB) * 32;
#pragma unroll
        for (int j = 0; j < 8; ++j) rdA[j] = *(const f32x4*)(rA + j * 4);
        if (doB) {
#pragma unroll
            for (int j = 0; j < 8; ++j) rdB[j] = *(const f32x4*)(rB + j * 4);
        }
        float numA = 0.f, ssqA = 0.f, numB = 0.f, ssqB = 0.f;
#pragma unroll
        for (int l = 0; l < 32; ++l) {
            float ve = v_s[(l * 16 + e) * 64 + lane];
            runA[l] += ve;
            float t = runA[l] * rdA[l >> 2][l & 3];
            numA += t * sr[l];
            ssqA += t * t;
            if (doB) {
                runB[l] += ve;
                float tb = runB[l] * rdB[l >> 2][l & 3];
                numB += tb * sr[l];
                ssqB += tb * tb;
            }
        }
        float scoreA = numA / (sqrtf(ssqA) * srn + 1e-15f);
        if (pA == pm) out[b * 1024 + d] = scoreA;   // wave-uniform branch
        else lmax = fmaxf(lmax, scoreA);
        if (doB) {
            float scoreB = numB / (sqrtf(ssqB) * srn + 1e-15f);
            if (pB == pm) out[b * 1024 + d] = scoreB;
            else lmax = fmaxf(lmax, scoreB);
        }
    }
#pragma unroll
    for (int off = 32; off >= 1; off >>= 1) lmax = fmaxf(lmax, __shfl_xor(lmax, off));
    if (lane == 0) wmax_s[wave] = lmax;
    __syncthreads();
    if (tid == 0) {
        float m = wmax_s[0];
#pragma unroll
        for (int w = 1; w < 8; ++w) m = fmaxf(m, wmax_s[w]);
        unsigned u = __float_as_uint(m);
        unsigned key = (u & 0x80000000u) ? ~u : (u | 0x80000000u);
        atomicMax(&negk[b], key);
    }
}

__global__ void k_init(unsigned* __restrict__ negk) {
    if (threadIdx.x < 16) negk[threadIdx.x] = 0u;
}

__global__ void k_negout(const unsigned* __restrict__ negk, float* __restrict__ out) {
    int i = threadIdx.x;
    if (i < 16) {
        unsigned key = negk[i];
        unsigned u = (key & 0x80000000u) ? (key ^ 0x80000000u) : ~key;
        out[16384 + i] = __uint_as_float(u);
    }
}

extern "C" void kernel_launch(void* const* d_in, const int* in_sizes, int n_in,
                              void* d_out, int out_size, void* d_ws, size_t ws_size,
                              hipStream_t stream) {
    const float* videos = (const float*)d_in[0];
    const float* sentences = (const float*)d_in[1];
    const float* Wv = (const float*)d_in[2];
    const float* bv = (const float*)d_in[3];
    const float* Ws = (const float*)d_in[4];
    const float* bs = (const float*)d_in[5];
    const int* ytrue = (const int*)d_in[6];
    float* out = (float*)d_out;

    char* ws = (char*)d_ws;
    size_t off = 0;
    auto alloc = [&](size_t bytes) {
        char* p = ws + off;
        off = (off + bytes + 255) & ~(size_t)255;
        return p;
    };
    f16* vh = (f16*)alloc(52428800);      // videos fp16 [6400][4096]
    f16* wvt = (f16*)alloc(8388608);      // Wv^T fp16 [1024][4096]
    f16* sh = (f16*)alloc(786432);        // sentences fp16 [512][768]
    f16* wst = (f16*)alloc(1572864);      // Ws^T fp16 [1024][768]
    float* Vr = (float*)alloc(26214400);  // [6400][1024] f32
    f16* Vrh = (f16*)alloc(13107200);     // [6400][1024] f16
    float* Sr = (float*)alloc(2097152);   // [512][1024] f32
    f16* Srh = (f16*)alloc(1048576);      // [512][1024] f16
    float* W = (float*)alloc(33554432);   // [16][32][16][1024] f32
    float* Mg = (float*)alloc(32768);     // [16][16][32]
    float* Eg = (float*)alloc(32768);
    float* EMg = (float*)alloc(32768);    // [16][32][16]
    float* rdeng = (float*)alloc(278528); // [16][136][32]
    float* SrNorm = (float*)alloc(65536); // [16][1024]
    unsigned* negk = (unsigned*)alloc(64);
    if (off > ws_size) return;

    hipLaunchKernelGGL(k_init, dim3(1), dim3(64), 0, stream, negk);
    hipLaunchKernelGGL(k_cast, dim3(6553600 / 256), dim3(256), 0, stream, videos, vh, 6553600);
    hipLaunchKernelGGL(k_cast, dim3(98304 / 256), dim3(256), 0, stream, sentences, sh, 98304);
    hipLaunchKernelGGL(k_transpose_cast, dim3(32, 128), dim3(256), 0, stream, Wv, wvt, 4096, 1024);
    hipLaunchKernelGGL(k_transpose_cast, dim3(32, 24), dim3(256), 0, stream, Ws, wst, 768, 1024);
    hipLaunchKernelGGL(k_gemm, dim3(8, 50), dim3(256), 0, stream, vh, wvt, bv, Vr, Vrh, 6400, 1024, 4096);
    hipLaunchKernelGGL(k_gemm, dim3(8, 4), dim3(256), 0, stream, sh, wst, bs, Sr, Srh, 512, 1024, 768);
    hipLaunchKernelGGL(k_srnorm, dim3(64), dim3(256), 0, stream, Sr, SrNorm);
    hipLaunchKernelGGL(k_seg, dim3(256), dim3(256), 0, stream, Vr, Vrh, Srh, W, Mg, Eg);
    hipLaunchKernelGGL(k_alpha, dim3(16), dim3(512), 0, stream, Mg, Eg, EMg, rdeng);
    hipLaunchKernelGGL(k_combine, dim3(256), dim3(512), 131072, stream, W, EMg, rdeng, Sr, SrNorm, ytrue, out, negk);
    hipLaunchKernelGGL(k_negout, dim3(1), dim3(64), 0, stream, negk, out);
}

// Round 4
// 333.696 us; speedup vs baseline: 1.5723x; 1.0809x over previous
//
#include <hip/hip_runtime.h>

typedef _Float16 f16;
typedef f16 f16x4 __attribute__((ext_vector_type(4)));
typedef f16 f16x8 __attribute__((ext_vector_type(8)));
typedef float f32x4 __attribute__((ext_vector_type(4)));

// ---------------- cast fp32 -> fp16 (vectorized) ----------------
__global__ void k_cast(const float* __restrict__ src, f16* __restrict__ dst, int n4) {
    int i = blockIdx.x * 256 + threadIdx.x;
    if (i < n4) {
        f32x4 v = *(const f32x4*)(src + (size_t)i * 4);
        f16x4 h = { (f16)v[0], (f16)v[1], (f16)v[2], (f16)v[3] };
        *(f16x4*)(dst + (size_t)i * 4) = h;
    }
}

// ---------------- transpose + cast: src[R][C] f32 -> dst[C][R] f16 ----------------
__global__ __launch_bounds__(256) void k_transpose_cast(const float* __restrict__ src,
                                                        f16* __restrict__ dst, int R, int C) {
    __shared__ float tile[32 * 33];
    int tx = threadIdx.x & 31, ty = threadIdx.x >> 5;
    int c0 = blockIdx.x * 32, r0 = blockIdx.y * 32;
#pragma unroll
    for (int i = 0; i < 4; ++i) {
        int r = ty + i * 8;
        tile[r * 33 + tx] = src[(size_t)(r0 + r) * C + c0 + tx];
    }
    __syncthreads();
#pragma unroll
    for (int i = 0; i < 4; ++i) {
        int rr = ty + i * 8;
        dst[(size_t)(c0 + rr) * R + r0 + tx] = (f16)tile[tx * 33 + rr];
    }
}

// ---------------- videos GEMM: Ch[6400][1024] = f16(A[6400][4096] @ Bt[1024][4096]^T + bias)
// BM=256 BN=128 BK=64, 512 thr (8 waves 2x4), triple-buffered LDS (144KB), depth-3
// prefetch with counted vmcnt (T4), raw s_barrier, T2 swizzle byte^=((row&7)<<4)
// (pre-swizzled global source + swizzled ds_read, rule #21), T5 setprio, XCD swizzle.
__global__ __launch_bounds__(512, 2) void k_gemm2(const f16* __restrict__ A, const f16* __restrict__ Bt,
                                                  const float* __restrict__ bias, f16* __restrict__ Ch) {
    constexpr int K = 4096, N = 1024;
    constexpr int BUF = 49152;  // 32KB A + 16KB B per buffer
    __shared__ __attribute__((aligned(16))) char smem[3 * BUF];
    const int tid = threadIdx.x;
    const int lane = tid & 63, wave = tid >> 6;
    const int wm = wave >> 2, wn = wave & 3;
    const int lr = lane & 15, lq = lane >> 4;
    // bijective XCD swizzle: nwg = 200 = 8 * 25
    const int orig = blockIdx.x;
    const int wg = (orig & 7) * 25 + (orig >> 3);
    const int mt = wg >> 3, nt = wg & 7;
    const int m0 = mt * 256, n0 = nt * 128;
    // staging constants: thread t owns 16B chunks at linear LDS (t + i*512)*16.
    // row = (t>>3) + i*64 ; chunk col c = t&7 ; swizzled source col c' = c ^ (row&7)
    const int srow = tid >> 3;
    const int scol = ((tid & 7) ^ ((tid >> 3) & 7)) * 8;  // f16 units
    const f16* aA = A + (size_t)(m0 + srow) * K + scol;
    const f16* aB = Bt + (size_t)(n0 + srow) * K + scol;
    constexpr int NT = K / 64;

    auto stage = [&](int bb, int kt) {
        const f16* a0 = aA + kt * 64;
        const f16* b0 = aB + kt * 64;
        char* la = smem + bb + tid * 16;
#pragma unroll
        for (int i = 0; i < 4; ++i)
            __builtin_amdgcn_global_load_lds(
                (const __attribute__((address_space(1))) void*)(a0 + (size_t)i * 64 * K),
                (__attribute__((address_space(3))) void*)(la + i * 8192), 16, 0, 0);
        char* lb = smem + bb + 32768 + tid * 16;
#pragma unroll
        for (int i = 0; i < 2; ++i)
            __builtin_amdgcn_global_load_lds(
                (const __attribute__((address_space(1))) void*)(b0 + (size_t)i * 64 * K),
                (__attribute__((address_space(3))) void*)(lb + i * 8192), 16, 0, 0);
    };

    f32x4 acc[8][2] = {};
    const int xa = (lr & 7) << 4;

    stage(0, 0);
    stage(BUF, 1);
    stage(2 * BUF, 2);
    asm volatile("s_waitcnt vmcnt(12)" ::: "memory");  // tile 0 landed (tiles 1,2 in flight)
    __builtin_amdgcn_s_barrier();

    int bb = 0;
    for (int t = 0; t < NT; ++t) {
        const char* Ab = smem + bb;
        const char* Bb = smem + bb + 32768;
#pragma unroll
        for (int ks = 0; ks < 2; ++ks) {
            const int co = (ks * 64 + lq * 16) ^ xa;
            f16x8 bf0 = *(const f16x8*)(Bb + (wn * 32 + lr) * 128 + co);
            f16x8 bf1 = *(const f16x8*)(Bb + (wn * 32 + 16 + lr) * 128 + co);
            __builtin_amdgcn_s_setprio(1);
#pragma unroll
            for (int m = 0; m < 8; ++m) {
                f16x8 af = *(const f16x8*)(Ab + (wm * 128 + m * 16 + lr) * 128 + co);
                acc[m][0] = __builtin_amdgcn_mfma_f32_16x16x32_f16(af, bf0, acc[m][0], 0, 0, 0);
                acc[m][1] = __builtin_amdgcn_mfma_f32_16x16x32_f16(af, bf1, acc[m][1], 0, 0, 0);
            }
            __builtin_amdgcn_s_setprio(0);
        }
        __builtin_amdgcn_s_barrier();  // all waves done reading buf bb
        if (t + 3 < NT) {
            stage(bb, t + 3);  // reuse just-freed buffer
            asm volatile("s_waitcnt vmcnt(12)" ::: "memory");  // tile t+1 landed
        } else if (t + 2 < NT) {
            asm volatile("s_waitcnt vmcnt(6)" ::: "memory");
        } else if (t + 1 < NT) {
            asm volatile("s_waitcnt vmcnt(0)" ::: "memory");
        }
        if (t + 1 < NT) {
            __builtin_amdgcn_s_barrier();
            __builtin_amdgcn_sched_barrier(0);
        }
        bb = (bb == 2 * BUF) ? 0 : bb + BUF;
    }

#pragma unroll
    for (int m = 0; m < 8; ++m) {
#pragma unroll
        for (int n = 0; n < 2; ++n) {
            int col = n0 + wn * 32 + n * 16 + lr;
            float bc = bias[col];
#pragma unroll
            for (int j = 0; j < 4; ++j) {
                int row = m0 + wm * 128 + m * 16 + lq * 4 + j;
                Ch[(size_t)row * N + col] = (f16)(acc[m][n][j] + bc);
            }
        }
    }
}

// ---------------- fp16 MFMA GEMM (sentences): C[M][N] f32 + Ch f16 ----------------
__global__ __launch_bounds__(256) void k_gemm(const f16* __restrict__ A, const f16* __restrict__ Bt,
                                              const float* __restrict__ bias, float* __restrict__ C,
                                              f16* __restrict__ Ch, int M, int N, int K) {
    __shared__ f16 As[128 * 64];
    __shared__ f16 Bs[128 * 64];
    const int tid = threadIdx.x;
    const int lane = tid & 63, wave = tid >> 6;
    const int wr = wave >> 1, wc = wave & 1;
    const int m0 = blockIdx.y * 128, n0 = blockIdx.x * 128;
    const int lr = lane & 15, lq = lane >> 4;
    f32x4 acc[4][4] = {};
    for (int k0 = 0; k0 < K; k0 += 64) {
        __syncthreads();
#pragma unroll
        for (int r = 0; r < 4; ++r) {
            int o = r * 4096 + tid * 16;
            int row = o >> 7;
            int kb = (o & 127) >> 1;
            __builtin_amdgcn_global_load_lds(
                (const __attribute__((address_space(1))) void*)(A + (size_t)(m0 + row) * K + k0 + kb),
                (__attribute__((address_space(3))) void*)((char*)As + o), 16, 0, 0);
        }
#pragma unroll
        for (int r = 0; r < 4; ++r) {
            int o = r * 4096 + tid * 16;
            int row = o >> 7;
            int kb = (o & 127) >> 1;
            __builtin_amdgcn_global_load_lds(
                (const __attribute__((address_space(1))) void*)(Bt + (size_t)(n0 + row) * K + k0 + kb),
                (__attribute__((address_space(3))) void*)((char*)Bs + o), 16, 0, 0);
        }
        __syncthreads();
#pragma unroll
        for (int ks = 0; ks < 2; ++ks) {
            f16x8 af[4], bf[4];
#pragma unroll
            for (int m = 0; m < 4; ++m)
                af[m] = *(const f16x8*)&As[(wr * 64 + m * 16 + lr) * 64 + ks * 32 + lq * 8];
#pragma unroll
            for (int n = 0; n < 4; ++n)
                bf[n] = *(const f16x8*)&Bs[(wc * 64 + n * 16 + lr) * 64 + ks * 32 + lq * 8];
#pragma unroll
            for (int m = 0; m < 4; ++m)
#pragma unroll
                for (int n = 0; n < 4; ++n)
                    acc[m][n] = __builtin_amdgcn_mfma_f32_16x16x32_f16(af[m], bf[n], acc[m][n], 0, 0, 0);
        }
    }
#pragma unroll
    for (int m = 0; m < 4; ++m) {
#pragma unroll
        for (int n = 0; n < 4; ++n) {
            int col = n0 + wc * 64 + n * 16 + lr;
            float bcol = bias[col];
#pragma unroll
            for (int j = 0; j < 4; ++j) {
                int row = m0 + wr * 64 + m * 16 + lq * 4 + j;
                float v = acc[m][n][j] + bcol;
                C[(size_t)row * N + col] = v;
                Ch[(size_t)row * N + col] = (f16)v;
            }
        }
    }
}

// ---------------- ||Sr[b,:,d]|| over L=32 ----------------
__global__ void k_srnorm(const float* __restrict__ Sr, float* __restrict__ SrNorm) {
    int idx = blockIdx.x * 256 + threadIdx.x; // 16384
    int b = idx >> 10, d = idx & 1023;
    float s = 0.f;
#pragma unroll
    for (int l = 0; l < 32; ++l) {
        float v = Sr[((size_t)(b * 32 + l)) * 1024 + d];
        s += v * v;
    }
    SrNorm[idx] = sqrtf(s);
}

// ---------------- per-(b,seg): S = Srh @ Vrh^T (MFMA), softmax stats, W = P @ Vrh ----------------
__global__ __launch_bounds__(256) void k_seg(const f16* __restrict__ Vrh, const f16* __restrict__ Srh,
                                             float* __restrict__ W, float* __restrict__ Mg,
                                             float* __restrict__ Eg) {
    const int b = blockIdx.x >> 4, k = blockIdx.x & 15;
    __shared__ float Sm[32 * 26];
    __shared__ float P[32 * 25];
    __shared__ float VrB[25 * 260];
    const int tid = threadIdx.x;
    const int lane = tid & 63, wave = tid >> 6;
    {
        const int mf = wave >> 1, nf = wave & 1;
        const int lr = lane & 15, lq = lane >> 4;
        f32x4 acc = {};
        const f16* arow = Srh + ((size_t)(b * 32 + mf * 16 + lr)) * 1024 + lq * 8;
        const f16* brow = Vrh + ((size_t)(b * 400 + k * 25 + nf * 16 + lr)) * 1024 + lq * 8;
        for (int k0 = 0; k0 < 1024; k0 += 32) {
            f16x8 a = *(const f16x8*)(arow + k0);
            f16x8 bb = *(const f16x8*)(brow + k0);
            acc = __builtin_amdgcn_mfma_f32_16x16x32_f16(a, bb, acc, 0, 0, 0);
        }
        int t = nf * 16 + lr;
        if (t < 25) {
#pragma unroll
            for (int j = 0; j < 4; ++j) {
                int l = mf * 16 + lq * 4 + j;
                Sm[l * 26 + t] = acc[j];
            }
        }
    }
    __syncthreads();
    if (tid < 32) {
        int l = tid;
        float m = Sm[l * 26];
        for (int t = 1; t < 25; ++t) m = fmaxf(m, Sm[l * 26 + t]);
        float e = 0.f;
        for (int t = 0; t < 25; ++t) {
            float p = __expf(Sm[l * 26 + t] - m);
            P[l * 25 + t] = p;
            e += p;
        }
        Mg[(b * 16 + k) * 32 + l] = m;
        Eg[(b * 16 + k) * 32 + l] = e;
    }
    __syncthreads();
    const int dl = tid & 63, q = tid >> 6;
    for (int c = 0; c < 4; ++c) {
        // stage Vrh[seg rows, 256-col chunk] -> f32 LDS, vectorized f16x4
#pragma unroll
        for (int ii = 0; ii < 7; ++ii) {
            int idx4 = tid + ii * 256;  // 1600 groups of 4
            if (idx4 < 1600) {
                int row = idx4 >> 6, d4 = (idx4 & 63) * 4;
                f16x4 h = *(const f16x4*)&Vrh[((size_t)(b * 400 + k * 25 + row)) * 1024 + c * 256 + d4];
                f32x4 f = { (float)h[0], (float)h[1], (float)h[2], (float)h[3] };
                *(f32x4*)&VrB[row * 260 + d4] = f;
            }
        }
        __syncthreads();
        f32x4 accw[8] = {};
        for (int t = 0; t < 25; ++t) {
            f32x4 v = *(const f32x4*)&VrB[t * 260 + dl * 4];
#pragma unroll
            for (int li = 0; li < 8; ++li) {
                float p = P[(q + li * 4) * 25 + t];
                accw[li][0] += p * v[0];
                accw[li][1] += p * v[1];
                accw[li][2] += p * v[2];
                accw[li][3] += p * v[3];
            }
        }
#pragma unroll
        for (int li = 0; li < 8; ++li) {
            int l = q + li * 4;
            *(f32x4*)&W[(((size_t)(b * 32 + l)) * 16 + k) * 1024 + c * 256 + dl * 4] = accw[li];
        }
        __syncthreads();
    }
}

// ---------------- per-b: EM = exp(M-G), rden[p][l] = 1/sum_{k in win} EM*E ----------------
__global__ __launch_bounds__(512) void k_alpha(const float* __restrict__ Mg, const float* __restrict__ Eg,
                                               float* __restrict__ EMg, float* __restrict__ rdeng) {
    const int b = blockIdx.x;
    __shared__ float EE[32 * 16];
    __shared__ int pS[136], pE[136];
    const int tid = threadIdx.x;
    if (tid < 136) {
        int s = 0, rem = tid;
        while (rem >= 16 - s) { rem -= 16 - s; ++s; }
        pS[tid] = s;
        pE[tid] = s + rem;
    }
    if (tid < 32) {
        int l = tid;
        float G = -1e30f;
#pragma unroll
        for (int k = 0; k < 16; ++k) G = fmaxf(G, Mg[(b * 16 + k) * 32 + l]);
#pragma unroll
        for (int k = 0; k < 16; ++k) {
            float em = __expf(Mg[(b * 16 + k) * 32 + l] - G);
            EMg[((size_t)(b * 32 + l)) * 16 + k] = em;
            EE[l * 16 + k] = em * Eg[(b * 16 + k) * 32 + l];
        }
    }
    __syncthreads();
    for (int it = tid; it < 136 * 32; it += 512) {
        int p = it >> 5, l = it & 31;
        float den = 0.f;
        int s = pS[p], e = pE[p];
        for (int k = s; k <= e; ++k) den += EE[l * 16 + k];
        rdeng[((size_t)(b * 136) + p) * 32 + l] = 1.0f / (den + 1e-30f);
    }
}

// ---------------- combine (atomic-free): wave owns s in {w, 15-w}, lane owns d ----------------
__global__ __launch_bounds__(512) void k_combine(const float* __restrict__ W, const float* __restrict__ EMg,
                                                 const float* __restrict__ rdeng, const float* __restrict__ Sr,
                                                 const float* __restrict__ SrNorm, const int* __restrict__ ytrue,
                                                 float* __restrict__ out, unsigned int* __restrict__ negk) {
    extern __shared__ float v_s[]; // [32][16][64] = 32768 floats
    __shared__ float wmax_s[8];
    const int b = blockIdx.x >> 4, dc = blockIdx.x & 15;
    const int tid = threadIdx.x, lane = tid & 63, wave = tid >> 6;
    const int d = dc * 64 + lane;

#pragma unroll 4
    for (int i = 0; i < 64; ++i) {
        int idx = tid + i * 512;
        int l = idx >> 10, k = (idx >> 6) & 15;
        float em = EMg[(b * 32 + l) * 16 + k];
        v_s[idx] = W[(((size_t)(b * 32 + l)) * 16 + k) * 1024 + dc * 64 + (idx & 63)] * em;
    }
    float sr[32];
#pragma unroll
    for (int l = 0; l < 32; ++l) sr[l] = Sr[((size_t)(b * 32 + l)) * 1024 + d];
    const float srn = SrNorm[b * 1024 + d];
    const int sy = ytrue[b * 2], ey = ytrue[b * 2 + 1];
    const int pm = sy * 16 - (sy * (sy - 1)) / 2 + (ey - sy);
    __syncthreads();

    const int sA = wave, sB = 15 - wave;
    const int pA0 = sA * 16 - (sA * (sA - 1)) / 2 - sA;
    const int pB0 = sB * 16 - (sB * (sB - 1)) / 2 - sB;
    float runA[32], runB[32];
#pragma unroll
    for (int l = 0; l < 32; ++l) { runA[l] = 0.f; runB[l] = 0.f; }
    float lmax = -1e30f;

    for (int e = sA; e < 16; ++e) {
        const bool doB = (e >= sB);
        const int pA = pA0 + e, pB = pB0 + e;
        f32x4 rdA[8], rdB[8];
        const float* rA = rdeng + ((size_t)b * 136 + pA) * 32;
        const float* rB = rdeng + ((size_t)b * 136 + pB) * 32;
#pragma unroll
        for (int j = 0; j < 8; ++j) rdA[j] = *(const f32x4*)(rA + j * 4);
        if (doB) {
#pragma unroll
            for (int j = 0; j < 8; ++j) rdB[j] = *(const f32x4*)(rB + j * 4);
        }
        float numA = 0.f, ssqA = 0.f, numB = 0.f, ssqB = 0.f;
#pragma unroll
        for (int l = 0; l < 32; ++l) {
            float ve = v_s[(l * 16 + e) * 64 + lane];
            runA[l] += ve;
            float t = runA[l] * rdA[l >> 2][l & 3];
            numA += t * sr[l];
            ssqA += t * t;
            if (doB) {
                runB[l] += ve;
                float tb = runB[l] * rdB[l >> 2][l & 3];
                numB += tb * sr[l];
                ssqB += tb * tb;
            }
        }
        float scoreA = numA / (sqrtf(ssqA) * srn + 1e-15f);
        if (pA == pm) out[b * 1024 + d] = scoreA;
        else lmax = fmaxf(lmax, scoreA);
        if (doB) {
            float scoreB = numB / (sqrtf(ssqB) * srn + 1e-15f);
            if (pB == pm) out[b * 1024 + d] = scoreB;
            else lmax = fmaxf(lmax, scoreB);
        }
    }
#pragma unroll
    for (int off = 32; off >= 1; off >>= 1) lmax = fmaxf(lmax, __shfl_xor(lmax, off));
    if (lane == 0) wmax_s[wave] = lmax;
    __syncthreads();
    if (tid == 0) {
        float m = wmax_s[0];
#pragma unroll
        for (int w = 1; w < 8; ++w) m = fmaxf(m, wmax_s[w]);
        unsigned u = __float_as_uint(m);
        unsigned key = (u & 0x80000000u) ? ~u : (u | 0x80000000u);
        atomicMax(&negk[b], key);
    }
}

__global__ void k_init(unsigned* __restrict__ negk) {
    if (threadIdx.x < 16) negk[threadIdx.x] = 0u;
}

__global__ void k_negout(const unsigned* __restrict__ negk, float* __restrict__ out) {
    int i = threadIdx.x;
    if (i < 16) {
        unsigned key = negk[i];
        unsigned u = (key & 0x80000000u) ? (key ^ 0x80000000u) : ~key;
        out[16384 + i] = __uint_as_float(u);
    }
}

extern "C" void kernel_launch(void* const* d_in, const int* in_sizes, int n_in,
                              void* d_out, int out_size, void* d_ws, size_t ws_size,
                              hipStream_t stream) {
    const float* videos = (const float*)d_in[0];
    const float* sentences = (const float*)d_in[1];
    const float* Wv = (const float*)d_in[2];
    const float* bv = (const float*)d_in[3];
    const float* Ws = (const float*)d_in[4];
    const float* bs = (const float*)d_in[5];
    const int* ytrue = (const int*)d_in[6];
    float* out = (float*)d_out;

    char* ws = (char*)d_ws;
    size_t off = 0;
    auto alloc = [&](size_t bytes) {
        char* p = ws + off;
        off = (off + bytes + 255) & ~(size_t)255;
        return p;
    };
    f16* vh = (f16*)alloc(52428800);      // videos fp16 [6400][4096]
    f16* wvt = (f16*)alloc(8388608);      // Wv^T fp16 [1024][4096]
    f16* sh = (f16*)alloc(786432);        // sentences fp16 [512][768]
    f16* wst = (f16*)alloc(1572864);      // Ws^T fp16 [1024][768]
    f16* Vrh = (f16*)alloc(13107200);     // [6400][1024] f16
    float* Sr = (float*)alloc(2097152);   // [512][1024] f32
    f16* Srh = (f16*)alloc(1048576);      // [512][1024] f16
    float* W = (float*)alloc(33554432);   // [16][32][16][1024] f32
    float* Mg = (float*)alloc(32768);     // [16][16][32]
    float* Eg = (float*)alloc(32768);
    float* EMg = (float*)alloc(32768);    // [16][32][16]
    float* rdeng = (float*)alloc(278528); // [16][136][32]
    float* SrNorm = (float*)alloc(65536); // [16][1024]
    unsigned* negk = (unsigned*)alloc(64);
    if (off > ws_size) return;

    hipLaunchKernelGGL(k_init, dim3(1), dim3(64), 0, stream, negk);
    hipLaunchKernelGGL(k_cast, dim3(6553600 / 256), dim3(256), 0, stream, videos, vh, 6553600);
    hipLaunchKernelGGL(k_cast, dim3(98304 / 256), dim3(256), 0, stream, sentences, sh, 98304);
    hipLaunchKernelGGL(k_transpose_cast, dim3(32, 128), dim3(256), 0, stream, Wv, wvt, 4096, 1024);
    hipLaunchKernelGGL(k_transpose_cast, dim3(32, 24), dim3(256), 0, stream, Ws, wst, 768, 1024);
    hipLaunchKernelGGL(k_gemm2, dim3(200), dim3(512), 0, stream, vh, wvt, bv, Vrh);
    hipLaunchKernelGGL(k_gemm, dim3(8, 4), dim3(256), 0, stream, sh, wst, bs, Sr, Srh, 512, 1024, 768);
    hipLaunchKernelGGL(k_srnorm, dim3(64), dim3(256), 0, stream, Sr, SrNorm);
    hipLaunchKernelGGL(k_seg, dim3(256), dim3(256), 0, stream, Vrh, Srh, W, Mg, Eg);
    hipLaunchKernelGGL(k_alpha, dim3(16), dim3(512), 0, stream, Mg, Eg, EMg, rdeng);
    hipLaunchKernelGGL(k_combine, dim3(256), dim3(512), 131072, stream, W, EMg, rdeng, Sr, SrNorm, ytrue, out, negk);
    hipLaunchKernelGGL(k_negout, dim3(1), dim3(64), 0, stream, negk, out);
}